// Round 1
// baseline (4809.792 us; speedup 1.0000x reference)
//
#include <hip/hip_runtime.h>
#include <stdint.h>

#define B_  64
#define T_  128
#define V_  16000
#define D_  64
#define H_  512
#define G4_ 2048
#define BT_ 8192

typedef __attribute__((ext_vector_type(8))) short   short8;
typedef __attribute__((ext_vector_type(4))) float   f32x4;
typedef __bf16 bf16x8 __attribute__((ext_vector_type(8)));

__device__ __forceinline__ unsigned short f2bf(float f) {
  union { float f; unsigned int u; } v; v.f = f;
  return (unsigned short)((v.u + 0x7fffu + ((v.u >> 16) & 1u)) >> 16);
}

__device__ __forceinline__ f32x4 mfma_bf16(short8 a, short8 b, f32x4 c) {
  return __builtin_amdgcn_mfma_f32_16x16x32_bf16(
      __builtin_bit_cast(bf16x8, a), __builtin_bit_cast(bf16x8, b), c, 0, 0, 0);
}

// ---------------------------------------------------------------- utilities
__global__ void __launch_bounds__(256) zero_kernel(int* __restrict__ p, int n) {
  int i = blockIdx.x * 256 + threadIdx.x;
  if (i < n) p[i] = 0;
}

__global__ void __launch_bounds__(256) gather_kernel(const int* __restrict__ batch,
    const float* __restrict__ feat, unsigned short* __restrict__ xb) {
  int i = blockIdx.x * 256 + threadIdx.x;      // exactly BT_*D_ threads
  int row = i >> 6, d = i & 63;
  xb[i] = f2bf(feat[(size_t)batch[row] * D_ + d]);
}

__global__ void __launch_bounds__(256) cvt_kernel(const float* __restrict__ s,
    unsigned short* __restrict__ d, int n) {
  for (int i = blockIdx.x * 256 + threadIdx.x; i < n; i += gridDim.x * 256)
    d[i] = f2bf(s[i]);
}

// ------------------------------------------------------- tiled bf16 GEMM
// C[M,N] = A[M,K] * B[N,K]^T (+ epilogue). 128x128 tile, 4 waves of 64x64.
// EPI==0: C = acc + b1[n] + b2[n]  (fp32 store, xg buffer)
// EPI==1: p = exp(acc + b1[n]); C = p; rowsum[m] += sum_n p  (projection)
template<int K, int EPI>
__global__ void __launch_bounds__(256) gemm_kernel(
    const unsigned short* __restrict__ A, const unsigned short* __restrict__ Bm,
    float* __restrict__ C, const float* __restrict__ b1, const float* __restrict__ b2,
    float* __restrict__ rowsum, int N)
{
  __shared__ unsigned short As[128 * 72];   // +8 bf16 pad per row (bank spread)
  __shared__ unsigned short Bs[128 * 72];
  const int tid = threadIdx.x;
  const int w = tid >> 6, l = tid & 63;
  const int m0 = blockIdx.x * 128, n0 = blockIdx.y * 128;
  const int mw = (w >> 1) * 64, nw = (w & 1) * 64;
  const int lr = l & 15, lk = (l >> 4) * 8, lq = (l >> 4) * 4;

  f32x4 acc[4][4];
#pragma unroll
  for (int i = 0; i < 4; i++)
#pragma unroll
    for (int j = 0; j < 4; j++) acc[i][j] = (f32x4)0.0f;

  for (int kk = 0; kk < K; kk += 64) {
    __syncthreads();
#pragma unroll
    for (int u0 = 0; u0 < 1024; u0 += 256) {
      int u = u0 + tid;
      int r = u >> 3, c8 = (u & 7) * 8;
      *(short8*)(&As[r * 72 + c8]) = *(const short8*)(&A[(size_t)(m0 + r) * K + kk + c8]);
      *(short8*)(&Bs[r * 72 + c8]) = *(const short8*)(&Bm[(size_t)(n0 + r) * K + kk + c8]);
    }
    __syncthreads();
#pragma unroll
    for (int ks = 0; ks < 64; ks += 32) {
      short8 af[4], bf[4];
#pragma unroll
      for (int i = 0; i < 4; i++)
        af[i] = *(const short8*)(&As[(mw + i * 16 + lr) * 72 + ks + lk]);
#pragma unroll
      for (int j = 0; j < 4; j++)
        bf[j] = *(const short8*)(&Bs[(nw + j * 16 + lr) * 72 + ks + lk]);
#pragma unroll
      for (int i = 0; i < 4; i++)
#pragma unroll
        for (int j = 0; j < 4; j++)
          acc[i][j] = mfma_bf16(af[i], bf[j], acc[i][j]);
    }
  }

  if (EPI == 0) {
#pragma unroll
    for (int i = 0; i < 4; i++)
#pragma unroll
      for (int j = 0; j < 4; j++) {
        int cc = n0 + nw + j * 16 + lr;
        float bb = b1[cc] + b2[cc];
#pragma unroll
        for (int r = 0; r < 4; r++) {
          int row = m0 + mw + i * 16 + lq + r;
          C[(size_t)row * N + cc] = acc[i][j][r] + bb;
        }
      }
  } else {
#pragma unroll
    for (int i = 0; i < 4; i++) {
      float ps[4] = {0.f, 0.f, 0.f, 0.f};
      int rowb = m0 + mw + i * 16 + lq;
#pragma unroll
      for (int j = 0; j < 4; j++) {
        int cc = n0 + nw + j * 16 + lr;
        float lb = b1[cc];
#pragma unroll
        for (int r = 0; r < 4; r++) {
          float p = __expf(acc[i][j][r] + lb);
          C[(size_t)(rowb + r) * N + cc] = p;
          ps[r] += p;
        }
      }
#pragma unroll
      for (int r = 0; r < 4; r++) {
        float sv = ps[r];
        sv += __shfl_xor(sv, 1, 64);
        sv += __shfl_xor(sv, 2, 64);
        sv += __shfl_xor(sv, 4, 64);
        sv += __shfl_xor(sv, 8, 64);
        if (lr == 0) atomicAdd(&rowsum[rowb + r], sv);
      }
    }
  }
}

// ------------------------------------------------------------- recurrence
// One LSTM layer, all T steps in one launch. grid = 4 groups (batch-16) x 32
// blocks; block owns h-cols [blk*16, blk*16+16) i.e. gate rows w*512+blk*16+..
// per wave. Whh resident in VGPRs; h handoff via agent-scope atomics + flags.
__global__ void __launch_bounds__(256) rnn_kernel(
    const float* __restrict__ xg, const unsigned short* __restrict__ Whh,
    unsigned short* __restrict__ y, const unsigned short* __restrict__ hinit,
    const float* __restrict__ cinit, unsigned short* __restrict__ hfin,
    float* __restrict__ cfin, int* __restrict__ flags)
{
  __shared__ unsigned short hstage[16 * 520];   // 16 batch rows x 512 (+8 pad)
  __shared__ float gbuf[4][16][17];
  __shared__ float cstate[256];
  __shared__ unsigned short htile[256];
  const int tid = threadIdx.x;
  const int w = tid >> 6, l = tid & 63;
  const int lr = l & 15, lq = l >> 4;
  const int g = blockIdx.x >> 5, blk = blockIdx.x & 31;
  const int bg = g * 16;
  int* flg = flags + g * T_;

  // persistent B fragments: wave w holds gate rows w*512 + blk*16 + lr, K=512
  short8 bfrag[16];
  {
    const unsigned short* wrow = Whh + (size_t)(w * H_ + blk * 16 + lr) * H_ + lq * 8;
#pragma unroll
    for (int kk = 0; kk < 16; kk++)
      bfrag[kk] = *(const short8*)(wrow + kk * 32);
  }
  cstate[tid] = cinit ? cinit[(size_t)(bg + (tid >> 4)) * H_ + blk * 16 + (tid & 15)]
                      : 0.0f;

  for (int t = 0; t < T_; t++) {
    if (t > 0 && tid == 0) {
      while (__hip_atomic_load(flg + (t - 1), __ATOMIC_ACQUIRE,
                               __HIP_MEMORY_SCOPE_AGENT) < 32) {}
    }
    __syncthreads();
    // stage h(t-1) -> LDS (bf16, padded rows)
    if (t == 0) {
      if (hinit) {
#pragma unroll
        for (int it = 0; it < 16; it++) {
          int idx = it * 256 + tid;
          int r = idx >> 8, d = idx & 255;
          *(unsigned int*)(&hstage[r * 520 + d * 2]) =
              ((const unsigned int*)(hinit + (size_t)(bg + r) * H_))[d];
        }
      } else {
#pragma unroll
        for (int it = 0; it < 16; it++) {
          int idx = it * 256 + tid;
          int r = idx >> 8, d = idx & 255;
          *(unsigned int*)(&hstage[r * 520 + d * 2]) = 0u;
        }
      }
    } else {
#pragma unroll
      for (int it = 0; it < 16; it++) {
        int idx = it * 256 + tid;
        int r = idx >> 8, d = idx & 255;
        unsigned int* src =
            (unsigned int*)(y + ((size_t)(bg + r) * T_ + (t - 1)) * H_) + d;
        *(unsigned int*)(&hstage[r * 520 + d * 2]) =
            __hip_atomic_load(src, __ATOMIC_RELAXED, __HIP_MEMORY_SCOPE_AGENT);
      }
    }
    __syncthreads();

    // gates = xg[t] + h(t-1) @ Whh^T  for this block's 16 batch x 16 cols/wave
    f32x4 acc;
    {
      const int col = w * H_ + blk * 16 + lr;
#pragma unroll
      for (int r = 0; r < 4; r++)
        acc[r] = xg[((size_t)(bg + lq * 4 + r) * T_ + t) * G4_ + col];
    }
#pragma unroll
    for (int kk = 0; kk < 16; kk++) {
      short8 af = *(const short8*)(&hstage[lr * 520 + kk * 32 + lq * 8]);
      acc = mfma_bf16(af, bfrag[kk], acc);
    }
#pragma unroll
    for (int r = 0; r < 4; r++)
      gbuf[w][lq * 4 + r][lr] = acc[r];
    __syncthreads();

    // cell update: one thread per (batch b, col c)
    {
      const int b = tid >> 4, c = tid & 15;
      float gi = gbuf[0][b][c], gf = gbuf[1][b][c];
      float gg = gbuf[2][b][c], go = gbuf[3][b][c];
      float si = 1.0f / (1.0f + __expf(-gi));
      float sf = 1.0f / (1.0f + __expf(-gf));
      float so = 1.0f / (1.0f + __expf(-go));
      float tg = 1.0f - 2.0f / (1.0f + __expf(2.0f * gg));   // tanh, inf-safe
      float cn = sf * cstate[tid] + si * tg;
      cstate[tid] = cn;
      float tc = 1.0f - 2.0f / (1.0f + __expf(2.0f * cn));
      float hv = so * tc;
      htile[tid] = f2bf(hv);
      if (t == T_ - 1) {
        if (cfin) cfin[(size_t)(bg + b) * H_ + blk * 16 + c] = cn;
        if (hfin) hfin[(size_t)(bg + b) * H_ + blk * 16 + c] = f2bf(hv);
      }
    }
    __syncthreads();
    // publish h tile (agent-scope so other XCDs' blocks see it)
    if (tid < 128) {
      int b = tid >> 3, cp = tid & 7;
      unsigned int v = ((const unsigned int*)htile)[tid];
      unsigned int* dst =
          (unsigned int*)(y + ((size_t)(bg + b) * T_ + t) * H_ + blk * 16) + cp;
      __hip_atomic_store(dst, v, __ATOMIC_RELAXED, __HIP_MEMORY_SCOPE_AGENT);
    }
    __syncthreads();   // vmcnt(0) drain: all stores complete before flag
    if (tid == 0)
      __hip_atomic_fetch_add(flg + t, 1, __ATOMIC_RELEASE, __HIP_MEMORY_SCOPE_AGENT);
  }
}

// --------------------------------------------------------------- softmax /S
__global__ void __launch_bounds__(256) norm_kernel(float* __restrict__ out,
    const float* __restrict__ rowsum) {
  int row = blockIdx.x >> 3, chunk = blockIdx.x & 7;
  int t = threadIdx.x;
  if (t >= 250) return;                        // 250*8 = 2000 elems per chunk
  float inv = 1.0f / rowsum[row];
  size_t base = (size_t)row * V_ + (size_t)chunk * 2000 + (size_t)t * 8;
  float4 a = *(float4*)(out + base);
  float4 b = *(float4*)(out + base + 4);
  a.x *= inv; a.y *= inv; a.z *= inv; a.w *= inv;
  b.x *= inv; b.y *= inv; b.z *= inv; b.w *= inv;
  *(float4*)(out + base) = a;
  *(float4*)(out + base + 4) = b;
}

// ------------------------------------------------------------------- host
extern "C" void kernel_launch(void* const* d_in, const int* in_sizes, int n_in,
                              void* d_out, int out_size, void* d_ws, size_t ws_size,
                              hipStream_t stream) {
  (void)in_sizes; (void)n_in; (void)out_size; (void)ws_size;
  const int*   batch    = (const int*)  d_in[0];
  const float* features = (const float*)d_in[1];
  const float* eWih0 = (const float*)d_in[2];
  const float* eWhh0 = (const float*)d_in[3];
  const float* ebih0 = (const float*)d_in[4];
  const float* ebhh0 = (const float*)d_in[5];
  const float* eWih1 = (const float*)d_in[6];
  const float* eWhh1 = (const float*)d_in[7];
  const float* ebih1 = (const float*)d_in[8];
  const float* ebhh1 = (const float*)d_in[9];
  const float* dWih0 = (const float*)d_in[10];
  const float* dWhh0 = (const float*)d_in[11];
  const float* dbih0 = (const float*)d_in[12];
  const float* dbhh0 = (const float*)d_in[13];
  const float* dWih1 = (const float*)d_in[14];
  const float* dWhh1 = (const float*)d_in[15];
  const float* dbih1 = (const float*)d_in[16];
  const float* dbhh1 = (const float*)d_in[17];
  const float* linW  = (const float*)d_in[18];
  const float* linb  = (const float*)d_in[19];
  float* out = (float*)d_out;

  char* ws = (char*)d_ws;
  size_t off = 0;
  auto alloc = [&](size_t bytes) -> void* {
    void* p = ws + off;
    off = (off + bytes + 255) & ~(size_t)255;
    return p;
  };
  int*            flags   = (int*)           alloc(4 * 4 * T_ * sizeof(int)); // 8 KB
  float*          rowsum  = (float*)         alloc(BT_ * sizeof(float));      // 32 KB
  unsigned short* xb      = (unsigned short*)alloc((size_t)BT_ * D_ * 2);
  unsigned short* Wih_e0b = (unsigned short*)alloc((size_t)G4_ * D_ * 2);
  unsigned short* Wih_d0b = (unsigned short*)alloc((size_t)G4_ * D_ * 2);
  unsigned short* Whh_e0b = (unsigned short*)alloc((size_t)G4_ * H_ * 2);
  unsigned short* Whh_e1b = (unsigned short*)alloc((size_t)G4_ * H_ * 2);
  unsigned short* Whh_d0b = (unsigned short*)alloc((size_t)G4_ * H_ * 2);
  unsigned short* Whh_d1b = (unsigned short*)alloc((size_t)G4_ * H_ * 2);
  unsigned short* Wih_e1b = (unsigned short*)alloc((size_t)G4_ * H_ * 2);
  unsigned short* Wih_d1b = (unsigned short*)alloc((size_t)G4_ * H_ * 2);
  unsigned short* linWb   = (unsigned short*)alloc((size_t)V_ * H_ * 2);
  float*          xg      = (float*)         alloc((size_t)BT_ * G4_ * 4);    // 64 MB
  unsigned short* yA      = (unsigned short*)alloc((size_t)BT_ * H_ * 2);
  unsigned short* yB      = (unsigned short*)alloc((size_t)BT_ * H_ * 2);
  unsigned short* hf_e0   = (unsigned short*)alloc((size_t)B_ * H_ * 2);
  float*          cf_e0   = (float*)         alloc((size_t)B_ * H_ * 4);
  unsigned short* hf_e1   = (unsigned short*)alloc((size_t)B_ * H_ * 2);
  float*          cf_e1   = (float*)         alloc((size_t)B_ * H_ * 4);

  // flags + rowsum are contiguous: zero both (2048 + 8192 dwords)
  zero_kernel<<<40, 256, 0, stream>>>(flags, 10240);
  gather_kernel<<<BT_ * D_ / 256, 256, 0, stream>>>(batch, features, xb);

  cvt_kernel<<<1024, 256, 0, stream>>>(eWih0, Wih_e0b, G4_ * D_);
  cvt_kernel<<<1024, 256, 0, stream>>>(dWih0, Wih_d0b, G4_ * D_);
  cvt_kernel<<<1024, 256, 0, stream>>>(eWhh0, Whh_e0b, G4_ * H_);
  cvt_kernel<<<1024, 256, 0, stream>>>(eWhh1, Whh_e1b, G4_ * H_);
  cvt_kernel<<<1024, 256, 0, stream>>>(dWhh0, Whh_d0b, G4_ * H_);
  cvt_kernel<<<1024, 256, 0, stream>>>(dWhh1, Whh_d1b, G4_ * H_);
  cvt_kernel<<<1024, 256, 0, stream>>>(eWih1, Wih_e1b, G4_ * H_);
  cvt_kernel<<<1024, 256, 0, stream>>>(dWih1, Wih_d1b, G4_ * H_);
  cvt_kernel<<<1024, 256, 0, stream>>>(linW, linWb, V_ * H_);

  dim3 blk256(256);
  dim3 gXG(BT_ / 128, G4_ / 128);     // (64,16)
  dim3 gPROJ(BT_ / 128, V_ / 128);    // (64,125)

  // encoder layer 0
  gemm_kernel<64, 0><<<gXG, blk256, 0, stream>>>(xb, Wih_e0b, xg, ebih0, ebhh0, rowsum, G4_);
  rnn_kernel<<<128, blk256, 0, stream>>>(xg, Whh_e0b, yA, nullptr, nullptr, hf_e0, cf_e0, flags + 0 * 512);
  // encoder layer 1
  gemm_kernel<512, 0><<<gXG, blk256, 0, stream>>>(yA, Wih_e1b, xg, ebih1, ebhh1, rowsum, G4_);
  rnn_kernel<<<128, blk256, 0, stream>>>(xg, Whh_e1b, yB, nullptr, nullptr, hf_e1, cf_e1, flags + 1 * 512);
  // decoder layer 0 (init = encoder layer-0 finals)
  gemm_kernel<64, 0><<<gXG, blk256, 0, stream>>>(xb, Wih_d0b, xg, dbih0, dbhh0, rowsum, G4_);
  rnn_kernel<<<128, blk256, 0, stream>>>(xg, Whh_d0b, yA, hf_e0, cf_e0, nullptr, nullptr, flags + 2 * 512);
  // decoder layer 1 (init = encoder layer-1 finals)
  gemm_kernel<512, 0><<<gXG, blk256, 0, stream>>>(yA, Wih_d1b, xg, dbih1, dbhh1, rowsum, G4_);
  rnn_kernel<<<128, blk256, 0, stream>>>(xg, Whh_d1b, yB, hf_e1, cf_e1, nullptr, nullptr, flags + 3 * 512);
  // projection + exp + row sums, then in-place normalize
  gemm_kernel<512, 1><<<gPROJ, blk256, 0, stream>>>(yB, linWb, out, linb, nullptr, rowsum, V_);
  norm_kernel<<<BT_ * 8, blk256, 0, stream>>>(out, rowsum);
}